// Round 1
// baseline (116.654 us; speedup 1.0000x reference)
//
#include <hip/hip_runtime.h>
#include <stdint.h>

#define A_DIM 8192
#define B_DIM 8192
#define K_CL  256

#define BM 64
#define BK 64
#define NSLAB 8
#define SLABK (B_DIM / NSLAB)   // 1024
#define NKS (SLABK / BK)        // 16

typedef short bf16x8 __attribute__((ext_vector_type(8)));
typedef float f32x4 __attribute__((ext_vector_type(4)));

__device__ __forceinline__ unsigned short f2bf(float f) {
    unsigned int u = __float_as_uint(f);
    u += 0x7fffu + ((u >> 16) & 1u);   // round-to-nearest-even (finite inputs)
    return (unsigned short)(u >> 16);
}

// ---------- prep 1: p_r (f32 [8192][256]) -> prT (bf16 [256][8192]) ----------
__global__ __launch_bounds__(256) void k_transpose_pr(const float* __restrict__ pr,
                                                      unsigned short* __restrict__ prT) {
    __shared__ unsigned short lt[64][66];   // [k_local][b_local], padded
    const int bidb = blockIdx.x >> 2;       // 128 b-tiles
    const int bidk = blockIdx.x & 3;        // 4 k-tiles
    const int b0 = bidb * 64, k0 = bidk * 64;
    const int t = threadIdx.x;
    const int tr = t >> 4, tc = t & 15;
#pragma unroll
    for (int q = 0; q < 4; q++) {
        int brow = q * 16 + tr;
        const float4 v = *(const float4*)(pr + (size_t)(b0 + brow) * K_CL + k0 + tc * 4);
        lt[tc * 4 + 0][brow] = f2bf(v.x);
        lt[tc * 4 + 1][brow] = f2bf(v.y);
        lt[tc * 4 + 2][brow] = f2bf(v.z);
        lt[tc * 4 + 3][brow] = f2bf(v.w);
    }
    __syncthreads();
#pragma unroll
    for (int q = 0; q < 4; q++) {
        int krow = q * 16 + tr;
        ushort4 o;
        o.x = lt[krow][tc * 4 + 0];
        o.y = lt[krow][tc * 4 + 1];
        o.z = lt[krow][tc * 4 + 2];
        o.w = lt[krow][tc * 4 + 3];
        *(ushort4*)(prT + (size_t)(k0 + krow) * B_DIM + b0 + tc * 4) = o;
    }
}

// ---------- prep 2: pl_dot[a] = sum_k p_l[a][k] / cp[k] ----------
__global__ __launch_bounds__(256) void k_pldot(const float* __restrict__ pl,
                                               const float* __restrict__ cp,
                                               float* __restrict__ pl_dot) {
    const int a = blockIdx.x;
    const int t = threadIdx.x;
    float v = pl[(size_t)a * K_CL + t] * (1.0f / cp[t]);
    for (int o = 32; o; o >>= 1) v += __shfl_down(v, o, 64);
    __shared__ float red[4];
    const int lane = t & 63, wv = t >> 6;
    if (lane == 0) red[wv] = v;
    __syncthreads();
    if (t == 0) pl_dot[a] = red[0] + red[1] + red[2] + red[3];
}

// ---------- main: partial Q via MFMA, fused scalar reduction ----------
__global__ __launch_bounds__(256) void k_main(const float* __restrict__ w,
                                              const float* __restrict__ pl,
                                              const unsigned short* __restrict__ prT,
                                              const float* __restrict__ cp,
                                              const float* __restrict__ pl_dot,
                                              float* __restrict__ out) {
    __shared__ unsigned short A_lds[2][BM * BK];
    __shared__ float pl_lds[BM];
    __shared__ float cl_lds[K_CL];
    __shared__ float red[4];

    const int bid = blockIdx.x;
    const int slab = bid & 7;       // consecutive bids -> different slabs -> XCD locality on prT
    const int m = bid >> 3;
    const int row0 = m * BM;
    const int bbase = slab * SLABK;

    const int tid = threadIdx.x;
    const int lane = tid & 63;
    const int wv = tid >> 6;
    const int n0w = wv * 64;

    if (tid < BM) pl_lds[tid] = pl_dot[row0 + tid];
    cl_lds[tid] = 1.0f / cp[tid];

    f32x4 zero = {0.f, 0.f, 0.f, 0.f};
    f32x4 acc[4][4];
#pragma unroll
    for (int i = 0; i < 4; i++)
#pragma unroll
        for (int j = 0; j < 4; j++) acc[i][j] = zero;

    const int srow = tid >> 4;                 // 0..15
    const float* wp = w + (size_t)row0 * B_DIM + bbase + (tid & 15) * 4;
    const unsigned short* prTb = prT + bbase;

    float4 wreg[4];
    float rs_acc = 0.f;

    auto load_stage = [&](int ks) {
#pragma unroll
        for (int q = 0; q < 4; q++) {
            int row = q * 16 + srow;
            wreg[q] = *(const float4*)(wp + (size_t)row * B_DIM + ks * BK);
        }
    };
    auto commit = [&](int buf) {
#pragma unroll
        for (int q = 0; q < 4; q++) {
            int row = q * 16 + srow;
            float4 v = wreg[q];
            rs_acc += (v.x + v.y + v.z + v.w) * pl_lds[row];
            unsigned int lo = (unsigned int)f2bf(v.x) | ((unsigned int)f2bf(v.y) << 16);
            unsigned int hi = (unsigned int)f2bf(v.z) | ((unsigned int)f2bf(v.w) << 16);
            int off = row * 128 + (tid & 15) * 8;
            off ^= (row & 7) << 4;             // bank-conflict swizzle
            *(uint2*)((char*)(&A_lds[buf][0]) + off) = make_uint2(lo, hi);
        }
    };

    load_stage(0);
    __syncthreads();   // pl_lds/cl_lds ready
    commit(0);
    __syncthreads();

    for (int ks = 0; ks < NKS; ++ks) {
        const int cur = ks & 1;
        if (ks + 1 < NKS) load_stage(ks + 1);
#pragma unroll
        for (int kk = 0; kk < 2; ++kk) {
            bf16x8 af[4], bfr[4];
#pragma unroll
            for (int mi = 0; mi < 4; mi++) {
                int row = mi * 16 + (lane & 15);
                int off = row * 128 + ((kk * 64 + (lane >> 4) * 16) ^ ((row & 7) << 4));
                af[mi] = *(const bf16x8*)((const char*)(&A_lds[cur][0]) + off);
            }
#pragma unroll
            for (int ni = 0; ni < 4; ni++) {
                int n = n0w + ni * 16 + (lane & 15);
                bfr[ni] = *(const bf16x8*)(prTb + (size_t)n * B_DIM + ks * BK + kk * 32 + (lane >> 4) * 8);
            }
#pragma unroll
            for (int mi = 0; mi < 4; mi++)
#pragma unroll
                for (int ni = 0; ni < 4; ni++)
                    acc[mi][ni] = __builtin_amdgcn_mfma_f32_16x16x32_bf16(af[mi], bfr[ni], acc[mi][ni], 0, 0, 0);
        }
        if (ks + 1 < NKS) commit(cur ^ 1);
        __syncthreads();
    }

    // epilogue: tot = rs_acc + sum Q*(1-2*pl)/cp
    float tot = rs_acc;
    const int rgrp = lane >> 4;
#pragma unroll
    for (int mi = 0; mi < 4; mi++) {
#pragma unroll
        for (int r = 0; r < 4; r++) {
            int arow = row0 + mi * 16 + rgrp * 4 + r;
            const float* plrow = pl + (size_t)arow * K_CL;
#pragma unroll
            for (int ni = 0; ni < 4; ni++) {
                int n = n0w + ni * 16 + (lane & 15);
                float q = acc[mi][ni][r];
                tot += q * (1.0f - 2.0f * plrow[n]) * cl_lds[n];
            }
        }
    }
    for (int o = 32; o; o >>= 1) tot += __shfl_down(tot, o, 64);
    if (lane == 0) red[wv] = tot;
    __syncthreads();
    if (tid == 0) atomicAdd(out, red[0] + red[1] + red[2] + red[3]);
}

extern "C" void kernel_launch(void* const* d_in, const int* in_sizes, int n_in,
                              void* d_out, int out_size, void* d_ws, size_t ws_size,
                              hipStream_t stream) {
    const float* w  = (const float*)d_in[0];
    const float* pl = (const float*)d_in[1];
    const float* pr = (const float*)d_in[2];
    const float* cp = (const float*)d_in[3];
    float* out = (float*)d_out;

    unsigned short* prT = (unsigned short*)d_ws;                         // 4 MB
    float* pl_dot = (float*)((char*)d_ws + (size_t)K_CL * B_DIM * 2);    // +32 KB

    hipMemsetAsync(d_out, 0, sizeof(float), stream);
    k_transpose_pr<<<dim3(512), dim3(256), 0, stream>>>(pr, prT);
    k_pldot<<<dim3(8192), dim3(256), 0, stream>>>(pl, cp, pl_dot);
    k_main<<<dim3(128 * NSLAB), dim3(256), 0, stream>>>(w, pl, prT, cp, pl_dot, out);
}